// Round 7
// baseline (490.044 us; speedup 1.0000x reference)
//
#include <hip/hip_runtime.h>
#include <hip/hip_fp16.h>

#define NN 100000
#define NE 1600000
#define D 128
#define NC 8
#define NBUCK 391   // ceil(NN / 256) buckets of 256 node-ids
#define CHUNK 4096  // edges per binning block

typedef _Float16 half8 __attribute__((ext_vector_type(8)));
typedef float f32x4 __attribute__((ext_vector_type(4)));

// ---------------- utility ----------------
__global__ void k_zero(int* __restrict__ p, int n) {
    int i = blockIdx.x * blockDim.x + threadIdx.x;
    if (i < n) p[i] = 0;
}

// ---------------- pass 0: global bucket histogram ----------------
__global__ __launch_bounds__(256) void k_bhist(const int* __restrict__ dst,
                                               int* __restrict__ gcount, int E) {
    __shared__ int h[NBUCK];
    for (int i = threadIdx.x; i < NBUCK; i += 256) h[i] = 0;
    __syncthreads();
    const int base0 = blockIdx.x * CHUNK;
#pragma unroll
    for (int i = 0; i < 4; ++i) {
        int e = base0 + i * 1024 + threadIdx.x * 4;
        if (e < E) {  // E % 4 == 0 -> full int4 safe
            int4 d4 = *(const int4*)&dst[e];
            atomicAdd(&h[d4.x >> 8], 1);
            atomicAdd(&h[d4.y >> 8], 1);
            atomicAdd(&h[d4.z >> 8], 1);
            atomicAdd(&h[d4.w >> 8], 1);
        }
    }
    __syncthreads();
    for (int i = threadIdx.x; i < NBUCK; i += 256) {
        int c = h[i];
        if (c) atomicAdd(&gcount[i], c);
    }
}

// ---------------- bucket scan (1 block, 512 threads) ----------------
__global__ void k_bscan(const int* __restrict__ gcount, int* __restrict__ bstart,
                        int* __restrict__ bcursor) {
    __shared__ int sd[512];
    int t = threadIdx.x;
    int v = (t < NBUCK) ? gcount[t] : 0;
    sd[t] = v;
    __syncthreads();
    for (int off = 1; off < 512; off <<= 1) {
        int y = (t >= off) ? sd[t - off] : 0;
        __syncthreads();
        sd[t] += y;
        __syncthreads();
    }
    int ex = sd[t] - v;  // exclusive prefix
    if (t <= NBUCK) bstart[t] = ex;   // bstart[NBUCK] == E
    if (t < NBUCK) bcursor[t] = ex;
}

// ---------------- pass 1: scatter edges into bucket-major staging ----------------
__global__ __launch_bounds__(256) void k_bscatter(const int* __restrict__ src,
                                                  const int* __restrict__ dst,
                                                  int* __restrict__ bcursor,
                                                  int2* __restrict__ staged, int E) {
    __shared__ int h[NBUCK];
    __shared__ int cur[NBUCK];
    const int t = threadIdx.x;
    for (int i = t; i < NBUCK; i += 256) h[i] = 0;
    __syncthreads();
    const int base0 = blockIdx.x * CHUNK;
    int4 d4[4], s4[4];
    bool val[4];
#pragma unroll
    for (int i = 0; i < 4; ++i) {
        int e = base0 + i * 1024 + t * 4;
        val[i] = e < E;
        if (val[i]) {
            d4[i] = *(const int4*)&dst[e];
            s4[i] = *(const int4*)&src[e];
            atomicAdd(&h[d4[i].x >> 8], 1);
            atomicAdd(&h[d4[i].y >> 8], 1);
            atomicAdd(&h[d4[i].z >> 8], 1);
            atomicAdd(&h[d4[i].w >> 8], 1);
        }
    }
    __syncthreads();
    // reserve a contiguous range per bucket for this block
    for (int i = t; i < NBUCK; i += 256) {
        int c = h[i];
        cur[i] = c ? atomicAdd(&bcursor[i], c) : 0;
    }
    __syncthreads();
#pragma unroll
    for (int i = 0; i < 4; ++i) {
        if (val[i]) {
            int p;
            p = atomicAdd(&cur[d4[i].x >> 8], 1); staged[p] = make_int2(s4[i].x, d4[i].x);
            p = atomicAdd(&cur[d4[i].y >> 8], 1); staged[p] = make_int2(s4[i].y, d4[i].y);
            p = atomicAdd(&cur[d4[i].z >> 8], 1); staged[p] = make_int2(s4[i].z, d4[i].z);
            p = atomicAdd(&cur[d4[i].w >> 8], 1); staged[p] = make_int2(s4[i].w, d4[i].w);
        }
    }
}

// ---------------- pass 2: per-bucket local CSR build (one block per bucket) ------
__global__ __launch_bounds__(256) void k_bfill(const int2* __restrict__ staged,
                                               const int* __restrict__ bstart,
                                               int* __restrict__ rowstart,
                                               int* __restrict__ cnt,
                                               float* __restrict__ dinv,
                                               int* __restrict__ csr) {
    const int b = blockIdx.x;
    const int t = threadIdx.x;
    const int bs = bstart[b], be = bstart[b + 1];
    __shared__ int lc[256];  // per-node count, later reused as cursor
    __shared__ int ls[256];  // per-node global csr start
    __shared__ int sd[256];  // scan temp
    lc[t] = 0;
    __syncthreads();
    for (int i = bs + t; i < be; i += 256) {
        int2 e = staged[i];
        atomicAdd(&lc[e.y & 255], 1);
    }
    __syncthreads();
    int v = lc[t];
    sd[t] = v;
    __syncthreads();
    for (int off = 1; off < 256; off <<= 1) {
        int y = (t >= off) ? sd[t - off] : 0;
        __syncthreads();
        sd[t] += y;
        __syncthreads();
    }
    int ex = sd[t] - v;
    ls[t] = bs + ex;
    int node = (b << 8) + t;
    if (node < NN) {
        rowstart[node] = bs + ex;
        cnt[node] = v;
        dinv[node] = rsqrtf((float)(v + 1));  // +1 = self-loop
    }
    lc[t] = 0;  // reuse as cursor
    __syncthreads();
    for (int i = bs + t; i < be; i += 256) {
        int2 e = staged[i];
        int li = e.y & 255;
        int p = atomicAdd(&lc[li], 1);
        csr[ls[li] + p] = e.x;
    }
}

// ---------------- W convert+transpose: wt[col][k] = half(W[k][col]) ----------------
__global__ void k_cvtw(const float* __restrict__ W, __half* __restrict__ wt) {
    int t = threadIdx.x;
    for (int i = t; i < D * D; i += 256) {
        int k = i >> 7, c = i & 127;
        wt[c * D + k] = __float2half(W[i]);
    }
}

// ---------------- MFMA GEMM with SLICED fp16 output -----------------------------
// hout layout: hout[slice][node][16] halves, slice = col>>4 (8 slices of 16 cols).
// 4 waves/block; wave = 16 rows x 64 cols (4 col-tiles x 4 K-steps of 16x16x32).
template <bool F32IN>
__global__ __launch_bounds__(256) void k_mgemm(const void* __restrict__ Ain,
                                               const __half* __restrict__ wt,
                                               const float* __restrict__ dinv,
                                               __half* __restrict__ hout) {
    const int tid = threadIdx.x;
    const int lane = tid & 63;
    const int wave = tid >> 6;
    const int wr = wave >> 1, wc = wave & 1;
    const int row0 = blockIdx.x * 32 + wr * 16;
    const int arow = row0 + (lane & 15);
    const int kg = lane >> 4;

    half8 afrag[4];
    if constexpr (F32IN) {
        const float* A = (const float*)Ain;
#pragma unroll
        for (int s = 0; s < 4; ++s) {
            const float* p = &A[(size_t)arow * D + s * 32 + kg * 8];
            float4 f0 = *(const float4*)p;
            float4 f1 = *(const float4*)(p + 4);
            half8 a;
            a[0] = (_Float16)f0.x; a[1] = (_Float16)f0.y;
            a[2] = (_Float16)f0.z; a[3] = (_Float16)f0.w;
            a[4] = (_Float16)f1.x; a[5] = (_Float16)f1.y;
            a[6] = (_Float16)f1.z; a[7] = (_Float16)f1.w;
            afrag[s] = a;
        }
    } else {
        const __half* A = (const __half*)Ain;
#pragma unroll
        for (int s = 0; s < 4; ++s)
            afrag[s] = *(const half8*)&A[(size_t)arow * D + s * 32 + kg * 8];
    }

    f32x4 acc[4] = {};
    const int colbase = wc * 64;
#pragma unroll
    for (int c = 0; c < 4; ++c) {
        const int col = colbase + c * 16 + (lane & 15);
#pragma unroll
        for (int s = 0; s < 4; ++s) {
            half8 b = *(const half8*)&wt[col * D + s * 32 + kg * 8];
            acc[c] = __builtin_amdgcn_mfma_f32_16x16x32_f16(afrag[s], b, acc[c], 0, 0, 0);
        }
    }

#pragma unroll
    for (int r = 0; r < 4; ++r) {
        const int row = row0 + kg * 4 + r;
        const float dv = dinv[row];
#pragma unroll
        for (int c = 0; c < 4; ++c) {
            const int col = colbase + c * 16 + (lane & 15);
            // sliced store: [col>>4][row][col&15]
            hout[((size_t)(col >> 4) * NN + row) * 16 + (col & 15)] =
                __float2half(acc[c][r] * dv);
        }
    }
}

__device__ inline void add8h(float* acc, float4 raw) {
    const __half2* hp = (const __half2*)&raw;
#pragma unroll
    for (int q = 0; q < 4; ++q) {
        float2 f = __half22float2(hp[q]);
        acc[2 * q] += f.x;
        acc[2 * q + 1] += f.y;
    }
}

// ---------------- aggregation v5: XCD-sliced gather ------------------------------
// hs layout: hs[slice][node][16] halves. Block handles slice = blockIdx & 7
// (consecutive blockIdx round-robin XCDs -> slice pinned to one XCD; its 3.2 MB
// slice is L2-resident). 8 nodes/block: each 32-lane half-wave owns one node;
// 16 slots x 2 parts (16B each). Output row-major fp16 [node][128].
__global__ __launch_bounds__(256) void k_aggs(const __half* __restrict__ hs,
                                              const int* __restrict__ rowstart,
                                              const int* __restrict__ cnt,
                                              const int* __restrict__ csr_src,
                                              const float* __restrict__ dinv,
                                              const float* __restrict__ bias,
                                              __half* __restrict__ out) {
    const int s = blockIdx.x & 7;
    const int node = (blockIdx.x >> 3) * 8 + (threadIdx.x >> 5);  // NN % 8 == 0
    const int l = threadIdx.x & 31;
    const int slot = l >> 1;   // 0..15 neighbor slots
    const int part = l & 1;    // which 16B half of the 32B slice

    const __half* __restrict__ base = hs + (size_t)s * NN * 16 + part * 8;

    float acc[8] = {};
    if (slot == 0) add8h(acc, *(const float4*)&base[(size_t)node * 16]);  // self-loop

    const int c = cnt[node];
    const int* __restrict__ cl = csr_src + rowstart[node];
    for (int t = slot; t < c; t += 16) {
        int sn = cl[t];
        add8h(acc, *(const float4*)&base[(size_t)sn * 16]);
    }

    // reduce across the 16 slots (offsets 2..16 stay within the 32-lane half)
#pragma unroll
    for (int off = 2; off <= 16; off <<= 1)
#pragma unroll
        for (int q = 0; q < 8; ++q) acc[q] += __shfl_xor(acc[q], off);

    if (slot == 0) {
        const float dv = dinv[node];
        const int f0 = s * 16 + part * 8;
        float4 b0 = *(const float4*)&bias[f0];
        float4 b1 = *(const float4*)&bias[f0 + 4];
        float r[8];
        r[0] = fmaxf(fmaf(dv, acc[0], b0.x), 0.f);
        r[1] = fmaxf(fmaf(dv, acc[1], b0.y), 0.f);
        r[2] = fmaxf(fmaf(dv, acc[2], b0.z), 0.f);
        r[3] = fmaxf(fmaf(dv, acc[3], b0.w), 0.f);
        r[4] = fmaxf(fmaf(dv, acc[4], b1.x), 0.f);
        r[5] = fmaxf(fmaf(dv, acc[5], b1.y), 0.f);
        r[6] = fmaxf(fmaf(dv, acc[6], b1.z), 0.f);
        r[7] = fmaxf(fmaf(dv, acc[7], b1.w), 0.f);
        union { float4 f; __half2 h[4]; } u;
#pragma unroll
        for (int q = 0; q < 4; ++q) u.h[q] = __floats2half2_rn(r[2 * q], r[2 * q + 1]);
        *(float4*)&out[(size_t)node * D + f0] = u.f;
    }
}

// ---------------- output: softmax(h @ Wout + bout), fp16 h ----------------
__global__ void k_out(const __half* __restrict__ h, const float* __restrict__ Wout,
                      const float* __restrict__ bout, float* __restrict__ out, int n) {
    __shared__ float ws[D * NC];
    int tid = threadIdx.x;
    for (int i = tid; i < D * NC; i += 256) ws[i] = Wout[i];
    __syncthreads();
    int node = blockIdx.x * 32 + (tid >> 3);
    int c = tid & 7;
    if (node >= n) return;
    float acc = bout[c];
    const __half* hrow = &h[(size_t)node * D];
#pragma unroll
    for (int k8 = 0; k8 < 16; ++k8) {
        float4 raw = *(const float4*)&hrow[k8 * 8];
        const __half2* hp = (const __half2*)&raw;
#pragma unroll
        for (int q = 0; q < 4; ++q) {
            float2 f = __half22float2(hp[q]);
            int k = k8 * 8 + 2 * q;
            acc += f.x * ws[k * NC + c] + f.y * ws[(k + 1) * NC + c];
        }
    }
    float m = acc;
#pragma unroll
    for (int off = 1; off < 8; off <<= 1) m = fmaxf(m, __shfl_xor(m, off));
    float e = __expf(acc - m);
    float ssum = e;
#pragma unroll
    for (int off = 1; off < 8; off <<= 1) ssum += __shfl_xor(ssum, off);
    out[(size_t)node * NC + c] = e / ssum;
}

// ---------------- launch ----------------
extern "C" void kernel_launch(void* const* d_in, const int* in_sizes, int n_in,
                              void* d_out, int out_size, void* d_ws, size_t ws_size,
                              hipStream_t stream) {
    const float* x    = (const float*)d_in[0];
    const int*   ei   = (const int*)d_in[1];   // [2][NE]: row 0 = src, row 1 = dst
    const float* W1   = (const float*)d_in[2];
    const float* b1   = (const float*)d_in[3];
    const float* W2   = (const float*)d_in[4];
    const float* b2   = (const float*)d_in[5];
    const float* Wout = (const float*)d_in[6];
    const float* bout = (const float*)d_in[7];
    float* out = (float*)d_out;

    size_t off = 0;
    char* base = (char*)d_ws;
    auto alloc = [&](size_t bytes) -> void* {
        void* p = base + off;
        off += (bytes + 255) & ~(size_t)255;
        return p;
    };
    int*    cnt      = (int*)alloc((size_t)NN * 4);
    int*    rowstart = (int*)alloc((size_t)NN * 4);
    int*    gcount   = (int*)alloc((size_t)(NBUCK + 1) * 4);
    int*    bstart   = (int*)alloc((size_t)(NBUCK + 1) * 4);
    int*    bcursor  = (int*)alloc((size_t)(NBUCK + 1) * 4);
    int*    csr      = (int*)alloc((size_t)NE * 4);
    float*  dinv     = (float*)alloc((size_t)NN * 4);
    __half* wt1      = (__half*)alloc((size_t)D * D * 2);
    __half* wt2      = (__half*)alloc((size_t)D * D * 2);
    __half* h16a     = (__half*)alloc((size_t)NN * D * 2);  // sliced gemm output
    __half* h16f     = (__half*)alloc((size_t)NN * D * 2);  // row-major agg1 output
    __half* h16b     = (__half*)alloc((size_t)NN * D * 2);  // row-major agg2 output
    int2*   staged   = (int2*)h16f;  // alias: consumed by k_bfill before h16f is written
    if (off > ws_size) return;  // workspace too small; fail visibly

    const int* src = ei;
    const int* dst = ei + NE;

    // ---- CSR build via bucketed counting sort ----
    int bin_grid = (NE + CHUNK - 1) / CHUNK;  // 391
    k_zero<<<2, 256, 0, stream>>>(gcount, NBUCK);
    k_bhist<<<bin_grid, 256, 0, stream>>>(dst, gcount, NE);
    k_bscan<<<1, 512, 0, stream>>>(gcount, bstart, bcursor);
    k_bscatter<<<bin_grid, 256, 0, stream>>>(src, dst, bcursor, staged, NE);
    k_bfill<<<NBUCK, 256, 0, stream>>>(staged, bstart, rowstart, cnt, dinv, csr);

    // ---- weight prep ----
    k_cvtw<<<1, 256, 0, stream>>>(W1, wt1);
    k_cvtw<<<1, 256, 0, stream>>>(W2, wt2);

    int gemm_grid = NN / 32;        // 3125 exactly
    int agg_grid = (NN / 8) * 8;    // 100000 blocks: slice = blockIdx&7, group = blockIdx>>3
    // layer 1
    k_mgemm<true><<<gemm_grid, 256, 0, stream>>>(x, wt1, dinv, h16a);
    k_aggs<<<agg_grid, 256, 0, stream>>>(h16a, rowstart, cnt, csr, dinv, b1, h16f);
    // layer 2
    k_mgemm<false><<<gemm_grid, 256, 0, stream>>>(h16f, wt2, dinv, h16a);
    k_aggs<<<agg_grid, 256, 0, stream>>>(h16a, rowstart, cnt, csr, dinv, b2, h16b);
    // output projection + softmax
    k_out<<<(NN + 31) / 32, 256, 0, stream>>>(h16b, Wout, bout, out, NN);
}

// Round 8
// 355.273 us; speedup vs baseline: 1.3793x; 1.3793x over previous
//
#include <hip/hip_runtime.h>
#include <hip/hip_fp16.h>

#define NN 100000
#define NE 1600000
#define D 128
#define NC 8
#define NBUCK 391   // ceil(NN / 256) buckets of 256 node-ids
#define CHUNK 4096  // edges per binning block

typedef _Float16 half8 __attribute__((ext_vector_type(8)));
typedef float f32x4 __attribute__((ext_vector_type(4)));

// ---------------- utility ----------------
__global__ void k_zero(int* __restrict__ p, int n) {
    int i = blockIdx.x * blockDim.x + threadIdx.x;
    if (i < n) p[i] = 0;
}

// ---------------- pass 0: global bucket histogram ----------------
__global__ __launch_bounds__(256) void k_bhist(const int* __restrict__ dst,
                                               int* __restrict__ gcount, int E) {
    __shared__ int h[NBUCK];
    for (int i = threadIdx.x; i < NBUCK; i += 256) h[i] = 0;
    __syncthreads();
    const int base0 = blockIdx.x * CHUNK;
#pragma unroll
    for (int i = 0; i < 4; ++i) {
        int e = base0 + i * 1024 + threadIdx.x * 4;
        if (e < E) {  // E % 4 == 0 -> full int4 safe
            int4 d4 = *(const int4*)&dst[e];
            atomicAdd(&h[d4.x >> 8], 1);
            atomicAdd(&h[d4.y >> 8], 1);
            atomicAdd(&h[d4.z >> 8], 1);
            atomicAdd(&h[d4.w >> 8], 1);
        }
    }
    __syncthreads();
    for (int i = threadIdx.x; i < NBUCK; i += 256) {
        int c = h[i];
        if (c) atomicAdd(&gcount[i], c);
    }
}

// ---------------- bucket scan (1 block, 512 threads) ----------------
__global__ void k_bscan(const int* __restrict__ gcount, int* __restrict__ bstart,
                        int* __restrict__ bcursor) {
    __shared__ int sd[512];
    int t = threadIdx.x;
    int v = (t < NBUCK) ? gcount[t] : 0;
    sd[t] = v;
    __syncthreads();
    for (int off = 1; off < 512; off <<= 1) {
        int y = (t >= off) ? sd[t - off] : 0;
        __syncthreads();
        sd[t] += y;
        __syncthreads();
    }
    int ex = sd[t] - v;  // exclusive prefix
    if (t <= NBUCK) bstart[t] = ex;   // bstart[NBUCK] == E
    if (t < NBUCK) bcursor[t] = ex;
}

// ---------------- pass 1: scatter edges into bucket-major staging ----------------
__global__ __launch_bounds__(256) void k_bscatter(const int* __restrict__ src,
                                                  const int* __restrict__ dst,
                                                  int* __restrict__ bcursor,
                                                  int2* __restrict__ staged, int E) {
    __shared__ int h[NBUCK];
    __shared__ int cur[NBUCK];
    const int t = threadIdx.x;
    for (int i = t; i < NBUCK; i += 256) h[i] = 0;
    __syncthreads();
    const int base0 = blockIdx.x * CHUNK;
    int4 d4[4], s4[4];
    bool val[4];
#pragma unroll
    for (int i = 0; i < 4; ++i) {
        int e = base0 + i * 1024 + t * 4;
        val[i] = e < E;
        if (val[i]) {
            d4[i] = *(const int4*)&dst[e];
            s4[i] = *(const int4*)&src[e];
            atomicAdd(&h[d4[i].x >> 8], 1);
            atomicAdd(&h[d4[i].y >> 8], 1);
            atomicAdd(&h[d4[i].z >> 8], 1);
            atomicAdd(&h[d4[i].w >> 8], 1);
        }
    }
    __syncthreads();
    // reserve a contiguous range per bucket for this block
    for (int i = t; i < NBUCK; i += 256) {
        int c = h[i];
        cur[i] = c ? atomicAdd(&bcursor[i], c) : 0;
    }
    __syncthreads();
#pragma unroll
    for (int i = 0; i < 4; ++i) {
        if (val[i]) {
            int p;
            p = atomicAdd(&cur[d4[i].x >> 8], 1); staged[p] = make_int2(s4[i].x, d4[i].x);
            p = atomicAdd(&cur[d4[i].y >> 8], 1); staged[p] = make_int2(s4[i].y, d4[i].y);
            p = atomicAdd(&cur[d4[i].z >> 8], 1); staged[p] = make_int2(s4[i].z, d4[i].z);
            p = atomicAdd(&cur[d4[i].w >> 8], 1); staged[p] = make_int2(s4[i].w, d4[i].w);
        }
    }
}

// ---------------- pass 2: per-bucket local CSR build (one block per bucket) ------
__global__ __launch_bounds__(256) void k_bfill(const int2* __restrict__ staged,
                                               const int* __restrict__ bstart,
                                               int* __restrict__ rowstart,
                                               int* __restrict__ cnt,
                                               float* __restrict__ dinv,
                                               int* __restrict__ csr) {
    const int b = blockIdx.x;
    const int t = threadIdx.x;
    const int bs = bstart[b], be = bstart[b + 1];
    __shared__ int lc[256];  // per-node count, later reused as cursor
    __shared__ int ls[256];  // per-node global csr start
    __shared__ int sd[256];  // scan temp
    lc[t] = 0;
    __syncthreads();
    for (int i = bs + t; i < be; i += 256) {
        int2 e = staged[i];
        atomicAdd(&lc[e.y & 255], 1);
    }
    __syncthreads();
    int v = lc[t];
    sd[t] = v;
    __syncthreads();
    for (int off = 1; off < 256; off <<= 1) {
        int y = (t >= off) ? sd[t - off] : 0;
        __syncthreads();
        sd[t] += y;
        __syncthreads();
    }
    int ex = sd[t] - v;
    ls[t] = bs + ex;
    int node = (b << 8) + t;
    if (node < NN) {
        rowstart[node] = bs + ex;
        cnt[node] = v;
        dinv[node] = rsqrtf((float)(v + 1));  // +1 = self-loop
    }
    lc[t] = 0;  // reuse as cursor
    __syncthreads();
    for (int i = bs + t; i < be; i += 256) {
        int2 e = staged[i];
        int li = e.y & 255;
        int p = atomicAdd(&lc[li], 1);
        csr[ls[li] + p] = e.x;
    }
}

// ---------------- W convert+transpose: wt[col][k] = half(W[k][col]) ----------------
__global__ void k_cvtw(const float* __restrict__ W, __half* __restrict__ wt) {
    int t = threadIdx.x;
    for (int i = t; i < D * D; i += 256) {
        int k = i >> 7, c = i & 127;
        wt[c * D + k] = __float2half(W[i]);
    }
}

// ---------------- MFMA GEMM with SLICED fp16 output -----------------------------
// hout layout: hout[slice][node][16] halves, slice = col>>4 (8 slices of 16 cols).
// 4 waves/block; wave = 16 rows x 64 cols (4 col-tiles x 4 K-steps of 16x16x32).
template <bool F32IN>
__global__ __launch_bounds__(256) void k_mgemm(const void* __restrict__ Ain,
                                               const __half* __restrict__ wt,
                                               const float* __restrict__ dinv,
                                               __half* __restrict__ hout) {
    const int tid = threadIdx.x;
    const int lane = tid & 63;
    const int wave = tid >> 6;
    const int wr = wave >> 1, wc = wave & 1;
    const int row0 = blockIdx.x * 32 + wr * 16;
    const int arow = row0 + (lane & 15);
    const int kg = lane >> 4;

    half8 afrag[4];
    if constexpr (F32IN) {
        const float* A = (const float*)Ain;
#pragma unroll
        for (int s = 0; s < 4; ++s) {
            const float* p = &A[(size_t)arow * D + s * 32 + kg * 8];
            float4 f0 = *(const float4*)p;
            float4 f1 = *(const float4*)(p + 4);
            half8 a;
            a[0] = (_Float16)f0.x; a[1] = (_Float16)f0.y;
            a[2] = (_Float16)f0.z; a[3] = (_Float16)f0.w;
            a[4] = (_Float16)f1.x; a[5] = (_Float16)f1.y;
            a[6] = (_Float16)f1.z; a[7] = (_Float16)f1.w;
            afrag[s] = a;
        }
    } else {
        const __half* A = (const __half*)Ain;
#pragma unroll
        for (int s = 0; s < 4; ++s)
            afrag[s] = *(const half8*)&A[(size_t)arow * D + s * 32 + kg * 8];
    }

    f32x4 acc[4] = {};
    const int colbase = wc * 64;
#pragma unroll
    for (int c = 0; c < 4; ++c) {
        const int col = colbase + c * 16 + (lane & 15);
#pragma unroll
        for (int s = 0; s < 4; ++s) {
            half8 b = *(const half8*)&wt[col * D + s * 32 + kg * 8];
            acc[c] = __builtin_amdgcn_mfma_f32_16x16x32_f16(afrag[s], b, acc[c], 0, 0, 0);
        }
    }

#pragma unroll
    for (int r = 0; r < 4; ++r) {
        const int row = row0 + kg * 4 + r;
        const float dv = dinv[row];
#pragma unroll
        for (int c = 0; c < 4; ++c) {
            const int col = colbase + c * 16 + (lane & 15);
            // sliced store: [col>>4][row][col&15]
            hout[((size_t)(col >> 4) * NN + row) * 16 + (col & 15)] =
                __float2half(acc[c][r] * dv);
        }
    }
}

__device__ inline void add8h(float* acc, float4 raw) {
    const __half2* hp = (const __half2*)&raw;
#pragma unroll
    for (int q = 0; q < 4; ++q) {
        float2 f = __half22float2(hp[q]);
        acc[2 * q] += f.x;
        acc[2 * q + 1] += f.y;
    }
}

// ---------------- aggregation v6: XCD-sliced gather, lane-serial ------------------
// hs layout: hs[slice][node][16] halves. slice = blockIdx & 7 (round-robin -> one
// XCD per slice; 3.2 MB slice is L2-resident). 2 lanes per node-slice (disjoint
// 8-feature parts -> NO cross-lane reduce). Each lane serially accumulates all c
// neighbors with a 4-deep unrolled prefetch. 128 node-slices per 256-thread block.
__global__ __launch_bounds__(256) void k_aggs(const __half* __restrict__ hs,
                                              const int* __restrict__ rowstart,
                                              const int* __restrict__ cnt,
                                              const int* __restrict__ csr_src,
                                              const float* __restrict__ dinv,
                                              const float* __restrict__ bias,
                                              __half* __restrict__ out) {
    const int s = blockIdx.x & 7;
    const int node = (blockIdx.x >> 3) * 128 + (threadIdx.x >> 1);
    if (node >= NN) return;
    const int part = threadIdx.x & 1;

    const __half* __restrict__ base = hs + (size_t)s * NN * 16 + part * 8;

    float acc[8] = {};
    add8h(acc, *(const float4*)&base[(size_t)node * 16]);  // self-loop

    const int c = cnt[node];
    const int* __restrict__ cl = csr_src + rowstart[node];

    int t = 0;
    for (; t + 4 <= c; t += 4) {
        const int s0 = cl[t], s1 = cl[t + 1], s2 = cl[t + 2], s3 = cl[t + 3];
        const float4 v0 = *(const float4*)&base[(size_t)s0 * 16];
        const float4 v1 = *(const float4*)&base[(size_t)s1 * 16];
        const float4 v2 = *(const float4*)&base[(size_t)s2 * 16];
        const float4 v3 = *(const float4*)&base[(size_t)s3 * 16];
        add8h(acc, v0); add8h(acc, v1); add8h(acc, v2); add8h(acc, v3);
    }
    for (; t < c; ++t) {
        add8h(acc, *(const float4*)&base[(size_t)cl[t] * 16]);
    }

    const float dv = dinv[node];
    const int f0 = s * 16 + part * 8;
    float4 b0 = *(const float4*)&bias[f0];
    float4 b1 = *(const float4*)&bias[f0 + 4];
    float r[8];
    r[0] = fmaxf(fmaf(dv, acc[0], b0.x), 0.f);
    r[1] = fmaxf(fmaf(dv, acc[1], b0.y), 0.f);
    r[2] = fmaxf(fmaf(dv, acc[2], b0.z), 0.f);
    r[3] = fmaxf(fmaf(dv, acc[3], b0.w), 0.f);
    r[4] = fmaxf(fmaf(dv, acc[4], b1.x), 0.f);
    r[5] = fmaxf(fmaf(dv, acc[5], b1.y), 0.f);
    r[6] = fmaxf(fmaf(dv, acc[6], b1.z), 0.f);
    r[7] = fmaxf(fmaf(dv, acc[7], b1.w), 0.f);
    union { float4 f; __half2 h[4]; } u;
#pragma unroll
    for (int q = 0; q < 4; ++q) u.h[q] = __floats2half2_rn(r[2 * q], r[2 * q + 1]);
    *(float4*)&out[(size_t)node * D + f0] = u.f;
}

// ---------------- output: softmax(h @ Wout + bout), fp16 h ----------------
__global__ void k_out(const __half* __restrict__ h, const float* __restrict__ Wout,
                      const float* __restrict__ bout, float* __restrict__ out, int n) {
    __shared__ float ws[D * NC];
    int tid = threadIdx.x;
    for (int i = tid; i < D * NC; i += 256) ws[i] = Wout[i];
    __syncthreads();
    int node = blockIdx.x * 32 + (tid >> 3);
    int c = tid & 7;
    if (node >= n) return;
    float acc = bout[c];
    const __half* hrow = &h[(size_t)node * D];
#pragma unroll
    for (int k8 = 0; k8 < 16; ++k8) {
        float4 raw = *(const float4*)&hrow[k8 * 8];
        const __half2* hp = (const __half2*)&raw;
#pragma unroll
        for (int q = 0; q < 4; ++q) {
            float2 f = __half22float2(hp[q]);
            int k = k8 * 8 + 2 * q;
            acc += f.x * ws[k * NC + c] + f.y * ws[(k + 1) * NC + c];
        }
    }
    float m = acc;
#pragma unroll
    for (int off = 1; off < 8; off <<= 1) m = fmaxf(m, __shfl_xor(m, off));
    float e = __expf(acc - m);
    float ssum = e;
#pragma unroll
    for (int off = 1; off < 8; off <<= 1) ssum += __shfl_xor(ssum, off);
    out[(size_t)node * NC + c] = e / ssum;
}

// ---------------- launch ----------------
extern "C" void kernel_launch(void* const* d_in, const int* in_sizes, int n_in,
                              void* d_out, int out_size, void* d_ws, size_t ws_size,
                              hipStream_t stream) {
    const float* x    = (const float*)d_in[0];
    const int*   ei   = (const int*)d_in[1];   // [2][NE]: row 0 = src, row 1 = dst
    const float* W1   = (const float*)d_in[2];
    const float* b1   = (const float*)d_in[3];
    const float* W2   = (const float*)d_in[4];
    const float* b2   = (const float*)d_in[5];
    const float* Wout = (const float*)d_in[6];
    const float* bout = (const float*)d_in[7];
    float* out = (float*)d_out;

    size_t off = 0;
    char* base = (char*)d_ws;
    auto alloc = [&](size_t bytes) -> void* {
        void* p = base + off;
        off += (bytes + 255) & ~(size_t)255;
        return p;
    };
    int*    cnt      = (int*)alloc((size_t)NN * 4);
    int*    rowstart = (int*)alloc((size_t)NN * 4);
    int*    gcount   = (int*)alloc((size_t)(NBUCK + 1) * 4);
    int*    bstart   = (int*)alloc((size_t)(NBUCK + 1) * 4);
    int*    bcursor  = (int*)alloc((size_t)(NBUCK + 1) * 4);
    int*    csr      = (int*)alloc((size_t)NE * 4);
    float*  dinv     = (float*)alloc((size_t)NN * 4);
    __half* wt1      = (__half*)alloc((size_t)D * D * 2);
    __half* wt2      = (__half*)alloc((size_t)D * D * 2);
    __half* h16a     = (__half*)alloc((size_t)NN * D * 2);  // sliced gemm output
    __half* h16f     = (__half*)alloc((size_t)NN * D * 2);  // row-major agg1 output
    __half* h16b     = (__half*)alloc((size_t)NN * D * 2);  // row-major agg2 output
    int2*   staged   = (int2*)h16f;  // alias: consumed by k_bfill before h16f is written
    if (off > ws_size) return;  // workspace too small; fail visibly

    const int* src = ei;
    const int* dst = ei + NE;

    // ---- CSR build via bucketed counting sort ----
    int bin_grid = (NE + CHUNK - 1) / CHUNK;  // 391
    k_zero<<<2, 256, 0, stream>>>(gcount, NBUCK);
    k_bhist<<<bin_grid, 256, 0, stream>>>(dst, gcount, NE);
    k_bscan<<<1, 512, 0, stream>>>(gcount, bstart, bcursor);
    k_bscatter<<<bin_grid, 256, 0, stream>>>(src, dst, bcursor, staged, NE);
    k_bfill<<<NBUCK, 256, 0, stream>>>(staged, bstart, rowstart, cnt, dinv, csr);

    // ---- weight prep ----
    k_cvtw<<<1, 256, 0, stream>>>(W1, wt1);
    k_cvtw<<<1, 256, 0, stream>>>(W2, wt2);

    int gemm_grid = NN / 32;                 // 3125 exactly
    int agg_grid = ((NN + 127) / 128) * 8;   // 782 node-groups x 8 slices = 6256
    // layer 1
    k_mgemm<true><<<gemm_grid, 256, 0, stream>>>(x, wt1, dinv, h16a);
    k_aggs<<<agg_grid, 256, 0, stream>>>(h16a, rowstart, cnt, csr, dinv, b1, h16f);
    // layer 2
    k_mgemm<false><<<gemm_grid, 256, 0, stream>>>(h16f, wt2, dinv, h16a);
    k_aggs<<<agg_grid, 256, 0, stream>>>(h16a, rowstart, cnt, csr, dinv, b2, h16b);
    // output projection + softmax
    k_out<<<(NN + 31) / 32, 256, 0, stream>>>(h16b, Wout, bout, out, NN);
}

// Round 9
// 326.045 us; speedup vs baseline: 1.5030x; 1.0896x over previous
//
#include <hip/hip_runtime.h>
#include <hip/hip_fp16.h>

#define NN 100000
#define NE 1600000
#define D 128
#define NC 8
#define NBUCK 391   // ceil(NN / 256) buckets of 256 node-ids
#define CHUNK 4096  // edges per binning block

typedef _Float16 half8 __attribute__((ext_vector_type(8)));
typedef float f32x4 __attribute__((ext_vector_type(4)));

// ---------------- pass 0: global bucket histogram ----------------
__global__ __launch_bounds__(256) void k_bhist(const int* __restrict__ dst,
                                               int* __restrict__ gcount, int E) {
    __shared__ int h[NBUCK];
    for (int i = threadIdx.x; i < NBUCK; i += 256) h[i] = 0;
    __syncthreads();
    const int base0 = blockIdx.x * CHUNK;
#pragma unroll
    for (int i = 0; i < 4; ++i) {
        int e = base0 + i * 1024 + threadIdx.x * 4;
        if (e < E) {  // E % 4 == 0 -> full int4 safe
            int4 d4 = *(const int4*)&dst[e];
            atomicAdd(&h[d4.x >> 8], 1);
            atomicAdd(&h[d4.y >> 8], 1);
            atomicAdd(&h[d4.z >> 8], 1);
            atomicAdd(&h[d4.w >> 8], 1);
        }
    }
    __syncthreads();
    for (int i = threadIdx.x; i < NBUCK; i += 256) {
        int c = h[i];
        if (c) atomicAdd(&gcount[i], c);
    }
}

// ---------------- bucket scan (1 block, 512 threads) ----------------
__global__ void k_bscan(const int* __restrict__ gcount, int* __restrict__ bstart,
                        int* __restrict__ bcursor) {
    __shared__ int sd[512];
    int t = threadIdx.x;
    int v = (t < NBUCK) ? gcount[t] : 0;
    sd[t] = v;
    __syncthreads();
    for (int off = 1; off < 512; off <<= 1) {
        int y = (t >= off) ? sd[t - off] : 0;
        __syncthreads();
        sd[t] += y;
        __syncthreads();
    }
    int ex = sd[t] - v;  // exclusive prefix
    if (t <= NBUCK) bstart[t] = ex;   // bstart[NBUCK] == E
    if (t < NBUCK) bcursor[t] = ex;
}

// ---------------- pass 1: scatter edges into bucket-major staging ----------------
__global__ __launch_bounds__(256) void k_bscatter(const int* __restrict__ src,
                                                  const int* __restrict__ dst,
                                                  int* __restrict__ bcursor,
                                                  int2* __restrict__ staged, int E) {
    __shared__ int h[NBUCK];
    __shared__ int cur[NBUCK];
    const int t = threadIdx.x;
    for (int i = t; i < NBUCK; i += 256) h[i] = 0;
    __syncthreads();
    const int base0 = blockIdx.x * CHUNK;
    int4 d4[4], s4[4];
    bool val[4];
#pragma unroll
    for (int i = 0; i < 4; ++i) {
        int e = base0 + i * 1024 + t * 4;
        val[i] = e < E;
        if (val[i]) {
            d4[i] = *(const int4*)&dst[e];
            s4[i] = *(const int4*)&src[e];
            atomicAdd(&h[d4[i].x >> 8], 1);
            atomicAdd(&h[d4[i].y >> 8], 1);
            atomicAdd(&h[d4[i].z >> 8], 1);
            atomicAdd(&h[d4[i].w >> 8], 1);
        }
    }
    __syncthreads();
    // reserve a contiguous range per bucket for this block
    for (int i = t; i < NBUCK; i += 256) {
        int c = h[i];
        cur[i] = c ? atomicAdd(&bcursor[i], c) : 0;
    }
    __syncthreads();
#pragma unroll
    for (int i = 0; i < 4; ++i) {
        if (val[i]) {
            int p;
            p = atomicAdd(&cur[d4[i].x >> 8], 1); staged[p] = make_int2(s4[i].x, d4[i].x);
            p = atomicAdd(&cur[d4[i].y >> 8], 1); staged[p] = make_int2(s4[i].y, d4[i].y);
            p = atomicAdd(&cur[d4[i].z >> 8], 1); staged[p] = make_int2(s4[i].z, d4[i].z);
            p = atomicAdd(&cur[d4[i].w >> 8], 1); staged[p] = make_int2(s4[i].w, d4[i].w);
        }
    }
}

// ---------------- pass 2: per-bucket local CSR build (one block per bucket) ------
__global__ __launch_bounds__(256) void k_bfill(const int2* __restrict__ staged,
                                               const int* __restrict__ bstart,
                                               int* __restrict__ rowstart,
                                               int* __restrict__ cnt,
                                               float* __restrict__ dinv,
                                               int* __restrict__ csr) {
    const int b = blockIdx.x;
    const int t = threadIdx.x;
    const int bs = bstart[b], be = bstart[b + 1];
    __shared__ int lc[256];  // per-node count, later reused as cursor
    __shared__ int ls[256];  // per-node global csr start
    __shared__ int sd[256];  // scan temp
    lc[t] = 0;
    __syncthreads();
    for (int i = bs + t; i < be; i += 256) {
        int2 e = staged[i];
        atomicAdd(&lc[e.y & 255], 1);
    }
    __syncthreads();
    int v = lc[t];
    sd[t] = v;
    __syncthreads();
    for (int off = 1; off < 256; off <<= 1) {
        int y = (t >= off) ? sd[t - off] : 0;
        __syncthreads();
        sd[t] += y;
        __syncthreads();
    }
    int ex = sd[t] - v;
    ls[t] = bs + ex;
    int node = (b << 8) + t;
    if (node < NN) {
        rowstart[node] = bs + ex;
        cnt[node] = v;
        dinv[node] = rsqrtf((float)(v + 1));  // +1 = self-loop
    }
    lc[t] = 0;  // reuse as cursor
    __syncthreads();
    for (int i = bs + t; i < be; i += 256) {
        int2 e = staged[i];
        int li = e.y & 255;
        int p = atomicAdd(&lc[li], 1);
        csr[ls[li] + p] = e.x;
    }
}

// ---------------- W convert+transpose (both weights in one launch) ---------------
// wt[col][k] = half(W[k][col]); blockIdx 0 -> (W1,wt1), 1 -> (W2,wt2)
__global__ void k_cvtw(const float* __restrict__ W1, __half* __restrict__ wt1,
                       const float* __restrict__ W2, __half* __restrict__ wt2) {
    const float* W = blockIdx.x ? W2 : W1;
    __half* wt = blockIdx.x ? wt2 : wt1;
    int t = threadIdx.x;
    for (int i = t; i < D * D; i += 256) {
        int k = i >> 7, c = i & 127;
        wt[c * D + k] = __float2half(W[i]);
    }
}

// ---------------- MFMA GEMM: hout[r] = half( (A[r] @ W) * dinv[r] ) ----------------
// 4 waves/block; wave = 16 rows x 64 cols (4 col-tiles x 4 K-steps of 16x16x32).
// Row-major fp16 output (r5-proven).
template <bool F32IN>
__global__ __launch_bounds__(256) void k_mgemm(const void* __restrict__ Ain,
                                               const __half* __restrict__ wt,
                                               const float* __restrict__ dinv,
                                               __half* __restrict__ hout) {
    const int tid = threadIdx.x;
    const int lane = tid & 63;
    const int wave = tid >> 6;
    const int wr = wave >> 1, wc = wave & 1;
    const int row0 = blockIdx.x * 32 + wr * 16;
    const int arow = row0 + (lane & 15);
    const int kg = lane >> 4;

    half8 afrag[4];
    if constexpr (F32IN) {
        const float* A = (const float*)Ain;
#pragma unroll
        for (int s = 0; s < 4; ++s) {
            const float* p = &A[(size_t)arow * D + s * 32 + kg * 8];
            float4 f0 = *(const float4*)p;
            float4 f1 = *(const float4*)(p + 4);
            half8 a;
            a[0] = (_Float16)f0.x; a[1] = (_Float16)f0.y;
            a[2] = (_Float16)f0.z; a[3] = (_Float16)f0.w;
            a[4] = (_Float16)f1.x; a[5] = (_Float16)f1.y;
            a[6] = (_Float16)f1.z; a[7] = (_Float16)f1.w;
            afrag[s] = a;
        }
    } else {
        const __half* A = (const __half*)Ain;
#pragma unroll
        for (int s = 0; s < 4; ++s)
            afrag[s] = *(const half8*)&A[(size_t)arow * D + s * 32 + kg * 8];
    }

    f32x4 acc[4] = {};
    const int colbase = wc * 64;
#pragma unroll
    for (int c = 0; c < 4; ++c) {
        const int col = colbase + c * 16 + (lane & 15);
#pragma unroll
        for (int s = 0; s < 4; ++s) {
            half8 b = *(const half8*)&wt[col * D + s * 32 + kg * 8];
            acc[c] = __builtin_amdgcn_mfma_f32_16x16x32_f16(afrag[s], b, acc[c], 0, 0, 0);
        }
    }

#pragma unroll
    for (int r = 0; r < 4; ++r) {
        const int row = row0 + kg * 4 + r;
        const float dv = dinv[row];
#pragma unroll
        for (int c = 0; c < 4; ++c) {
            const int col = colbase + c * 16 + (lane & 15);
            hout[(size_t)row * D + col] = __float2half(acc[c][r] * dv);
        }
    }
}

__device__ inline void add8h(float* acc, float4 raw) {
    const __half2* hp = (const __half2*)&raw;
#pragma unroll
    for (int q = 0; q < 4; ++q) {
        float2 f = __half22float2(hp[q]);
        acc[2 * q] += f.x;
        acc[2 * q + 1] += f.y;
    }
}

// ---------------- aggregation: row-major fp16 gather, one wave per node ----------
// 16 lanes x 16B cover a 128-half row; 4 neighbor-groups; prefetch 8 rows/group
// before accumulating (32 rows in flight/wave). out = relu(dinv*(self+sum)+b).
// MODE 0: write fp16 row. MODE 1: fused head softmax(row @ Wout + bout) -> fout.
// Head uses TRANSPOSED LDS wst[c][k]: lane stride 32B -> worst 4-way bank conflict
// (vs r6's 16-way pile-up on ws[k][c], which cost 2.2e7 conflict cycles).
template <int MODE>
__global__ __launch_bounds__(256) void k_agg(const __half* __restrict__ hs,
                                             const int* __restrict__ rowstart,
                                             const int* __restrict__ cnt,
                                             const int* __restrict__ csr_src,
                                             const float* __restrict__ dinv,
                                             const float* __restrict__ bias,
                                             __half* __restrict__ hout,
                                             float* __restrict__ fout,
                                             const float* __restrict__ Wout,
                                             const float* __restrict__ bout) {
    __shared__ float wst[MODE == 1 ? NC * D : 1];
    if constexpr (MODE == 1) {
        for (int i = threadIdx.x; i < NC * D; i += 256) {
            int c = i >> 7, k = i & 127;
            wst[c * D + k] = Wout[k * NC + c];
        }
        __syncthreads();
    }
    const int node = blockIdx.x * 4 + (threadIdx.x >> 6);  // NN % 4 == 0, exact grid
    const int lane = threadIdx.x & 63;
    const int g = lane >> 4;           // neighbor group 0..3
    const int f8 = (lane & 15) << 3;   // feature offset (8 halves = 16B per lane)

    float acc[8] = {};
    if (g == 0) add8h(acc, *(const float4*)&hs[(size_t)node * D + f8]);  // self-loop

    const int c = cnt[node];
    const int* __restrict__ cl = csr_src + rowstart[node];

    // group g owns neighbors g, g+4, g+8, ...; prefetch 8 per pass
    int t = g;
    while (t < c) {
        float4 v[8];
#pragma unroll
        for (int i = 0; i < 8; ++i) {
            int tt = t + 4 * i;
            if (tt < c) {
                int s = cl[tt];
                v[i] = *(const float4*)&hs[(size_t)s * D + f8];
            }
        }
#pragma unroll
        for (int i = 0; i < 8; ++i) {
            int tt = t + 4 * i;
            if (tt < c) add8h(acc, v[i]);
        }
        t += 32;
    }

    // combine the 4 groups
#pragma unroll
    for (int q = 0; q < 8; ++q) {
        acc[q] += __shfl_xor(acc[q], 16);
        acc[q] += __shfl_xor(acc[q], 32);
    }

    if (g == 0) {
        const float dv = dinv[node];
        float r[8];
#pragma unroll
        for (int q = 0; q < 8; ++q) r[q] = fmaxf(fmaf(dv, acc[q], bias[f8 + q]), 0.f);

        if constexpr (MODE == 0) {
            union { float4 f; __half2 h[4]; } u;
#pragma unroll
            for (int q = 0; q < 4; ++q) u.h[q] = __floats2half2_rn(r[2 * q], r[2 * q + 1]);
            *(float4*)&hout[(size_t)node * D + f8] = u.f;
        } else {
            // per-lane partial logits over this lane's 8 features (transposed LDS)
            float lg[NC] = {};
#pragma unroll
            for (int c8 = 0; c8 < NC; ++c8) {
                const float* wrow = &wst[c8 * D + f8];
#pragma unroll
                for (int q = 0; q < 8; ++q) lg[c8] = fmaf(r[q], wrow[q], lg[c8]);
            }
            // reduce across the 16 lanes of group 0 (stays within lanes 0..15)
#pragma unroll
            for (int off = 1; off < 16; off <<= 1)
#pragma unroll
                for (int c8 = 0; c8 < NC; ++c8) lg[c8] += __shfl_xor(lg[c8], off);
            // softmax (redundant on all 16 lanes; lane 0 writes)
            float m = -1e30f;
#pragma unroll
            for (int c8 = 0; c8 < NC; ++c8) { lg[c8] += bout[c8]; m = fmaxf(m, lg[c8]); }
            float ssum = 0.f;
#pragma unroll
            for (int c8 = 0; c8 < NC; ++c8) { lg[c8] = __expf(lg[c8] - m); ssum += lg[c8]; }
            float inv = 1.0f / ssum;
            if ((lane & 15) == 0) {
                float4 o0 = make_float4(lg[0] * inv, lg[1] * inv, lg[2] * inv, lg[3] * inv);
                float4 o1 = make_float4(lg[4] * inv, lg[5] * inv, lg[6] * inv, lg[7] * inv);
                *(float4*)&fout[(size_t)node * NC] = o0;
                *(float4*)&fout[(size_t)node * NC + 4] = o1;
            }
        }
    }
}

// ---------------- launch ----------------
extern "C" void kernel_launch(void* const* d_in, const int* in_sizes, int n_in,
                              void* d_out, int out_size, void* d_ws, size_t ws_size,
                              hipStream_t stream) {
    const float* x    = (const float*)d_in[0];
    const int*   ei   = (const int*)d_in[1];   // [2][NE]: row 0 = src, row 1 = dst
    const float* W1   = (const float*)d_in[2];
    const float* b1   = (const float*)d_in[3];
    const float* W2   = (const float*)d_in[4];
    const float* b2   = (const float*)d_in[5];
    const float* Wout = (const float*)d_in[6];
    const float* bout = (const float*)d_in[7];
    float* out = (float*)d_out;

    size_t off = 0;
    char* base = (char*)d_ws;
    auto alloc = [&](size_t bytes) -> void* {
        void* p = base + off;
        off += (bytes + 255) & ~(size_t)255;
        return p;
    };
    int*    cnt      = (int*)alloc((size_t)NN * 4);
    int*    rowstart = (int*)alloc((size_t)NN * 4);
    int*    gcount   = (int*)alloc((size_t)(NBUCK + 1) * 4);
    int*    bstart   = (int*)alloc((size_t)(NBUCK + 1) * 4);
    int*    bcursor  = (int*)alloc((size_t)(NBUCK + 1) * 4);
    int*    csr      = (int*)alloc((size_t)NE * 4);
    float*  dinv     = (float*)alloc((size_t)NN * 4);
    __half* wt1      = (__half*)alloc((size_t)D * D * 2);
    __half* wt2      = (__half*)alloc((size_t)D * D * 2);
    __half* h16a     = (__half*)alloc((size_t)NN * D * 2);  // gemm output (row-major)
    __half* h16f     = (__half*)alloc((size_t)NN * D * 2);  // agg1 output (row-major)
    int2*   staged   = (int2*)h16f;  // alias: consumed by k_bfill before h16f is written
    if (off > ws_size) return;  // workspace too small; fail visibly

    const int* src = ei;
    const int* dst = ei + NE;

    // ---- CSR build via bucketed counting sort ----
    int bin_grid = (NE + CHUNK - 1) / CHUNK;  // 391
    hipMemsetAsync(gcount, 0, (size_t)NBUCK * 4, stream);
    k_bhist<<<bin_grid, 256, 0, stream>>>(dst, gcount, NE);
    k_bscan<<<1, 512, 0, stream>>>(gcount, bstart, bcursor);
    k_bscatter<<<bin_grid, 256, 0, stream>>>(src, dst, bcursor, staged, NE);
    k_bfill<<<NBUCK, 256, 0, stream>>>(staged, bstart, rowstart, cnt, dinv, csr);

    // ---- weight prep (both in one launch) ----
    k_cvtw<<<2, 256, 0, stream>>>(W1, wt1, W2, wt2);

    int gemm_grid = NN / 32;   // 3125 exactly
    int agg_grid = NN / 4;     // 25000 exactly
    // layer 1
    k_mgemm<true><<<gemm_grid, 256, 0, stream>>>(x, wt1, dinv, h16a);
    k_agg<0><<<agg_grid, 256, 0, stream>>>(h16a, rowstart, cnt, csr, dinv, b1,
                                           h16f, nullptr, nullptr, nullptr);
    // layer 2 + fused classifier head -> d_out
    k_mgemm<false><<<gemm_grid, 256, 0, stream>>>(h16f, wt2, dinv, h16a);
    k_agg<1><<<agg_grid, 256, 0, stream>>>(h16a, rowstart, cnt, csr, dinv, b2,
                                           nullptr, out, Wout, bout);
}

// Round 10
// 267.110 us; speedup vs baseline: 1.8346x; 1.2206x over previous
//
#include <hip/hip_runtime.h>
#include <hip/hip_fp16.h>

#define NN 100000
#define NE 1600000
#define D 128
#define NC 8
#define NBUCK 391   // ceil(NN / 256) buckets of 256 node-ids
#define BCAP 6144   // fixed bucket capacity (mean 4092, sigma ~64 -> huge margin)
#define CHUNK 4096  // edges per binning block

typedef _Float16 half8 __attribute__((ext_vector_type(8)));
typedef float f32x4 __attribute__((ext_vector_type(4)));

// ---------------- pass 1: scatter edges into fixed-capacity buckets --------------
// staged[b*BCAP + pos] = src*256 | (dst&255)  (packed int32; src<2^17)
__global__ __launch_bounds__(256) void k_bscatter(const int* __restrict__ src,
                                                  const int* __restrict__ dst,
                                                  int* __restrict__ bcursor,
                                                  int* __restrict__ staged, int E) {
    __shared__ int h[NBUCK];
    __shared__ int cur[NBUCK];
    const int t = threadIdx.x;
    for (int i = t; i < NBUCK; i += 256) h[i] = 0;
    __syncthreads();
    const int base0 = blockIdx.x * CHUNK;
    int4 d4[4], s4[4];
    bool val[4];
#pragma unroll
    for (int i = 0; i < 4; ++i) {
        int e = base0 + i * 1024 + t * 4;
        val[i] = e < E;  // E % 4 == 0 -> full int4 safe
        if (val[i]) {
            d4[i] = *(const int4*)&dst[e];
            s4[i] = *(const int4*)&src[e];
            atomicAdd(&h[d4[i].x >> 8], 1);
            atomicAdd(&h[d4[i].y >> 8], 1);
            atomicAdd(&h[d4[i].z >> 8], 1);
            atomicAdd(&h[d4[i].w >> 8], 1);
        }
    }
    __syncthreads();
    // reserve a contiguous range per bucket for this block (global cursor)
    for (int i = t; i < NBUCK; i += 256) {
        int c = h[i];
        cur[i] = c ? (i * BCAP + atomicAdd(&bcursor[i], c)) : 0;
    }
    __syncthreads();
#pragma unroll
    for (int i = 0; i < 4; ++i) {
        if (val[i]) {
            int p;
            p = atomicAdd(&cur[d4[i].x >> 8], 1); staged[p] = s4[i].x * 256 + (d4[i].x & 255);
            p = atomicAdd(&cur[d4[i].y >> 8], 1); staged[p] = s4[i].y * 256 + (d4[i].y & 255);
            p = atomicAdd(&cur[d4[i].z >> 8], 1); staged[p] = s4[i].z * 256 + (d4[i].z & 255);
            p = atomicAdd(&cur[d4[i].w >> 8], 1); staged[p] = s4[i].w * 256 + (d4[i].w & 255);
        }
    }
}

// ---------------- pass 2: per-bucket local CSR build (one block per bucket) ------
// csr/rowstart are bucket-padded (bucket b owns [b*BCAP, b*BCAP+cnt_b)); rowstart
// holds ABSOLUTE offsets so downstream kernels are unchanged.
// Extra blocks b >= NBUCK do the weight convert+transpose (merged k_cvtw).
__global__ __launch_bounds__(256) void k_bfill(const int* __restrict__ staged,
                                               const int* __restrict__ bcursor,
                                               int* __restrict__ rowstart,
                                               int* __restrict__ cnt,
                                               float* __restrict__ dinv,
                                               int* __restrict__ csr,
                                               const float* __restrict__ W1,
                                               __half* __restrict__ wt1,
                                               const float* __restrict__ W2,
                                               __half* __restrict__ wt2) {
    const int b = blockIdx.x;
    const int t = threadIdx.x;
    if (b >= NBUCK) {  // merged weight prep: wt[col][k] = half(W[k][col])
        const float* W = (b - NBUCK) ? W2 : W1;
        __half* wt = (b - NBUCK) ? wt2 : wt1;
        for (int i = t; i < D * D; i += 256) {
            int k = i >> 7, c = i & 127;
            wt[c * D + k] = __float2half(W[i]);
        }
        return;
    }
    const int bs = b * BCAP;
    const int be = bs + bcursor[b];
    __shared__ int lc[256];  // per-node count, later reused as cursor
    __shared__ int ls[256];  // per-node global csr start
    __shared__ int sd[256];  // scan temp
    lc[t] = 0;
    __syncthreads();
    for (int i = bs + t; i < be; i += 256) {
        atomicAdd(&lc[staged[i] & 255], 1);
    }
    __syncthreads();
    int v = lc[t];
    sd[t] = v;
    __syncthreads();
    for (int off = 1; off < 256; off <<= 1) {
        int y = (t >= off) ? sd[t - off] : 0;
        __syncthreads();
        sd[t] += y;
        __syncthreads();
    }
    int ex = sd[t] - v;
    ls[t] = bs + ex;
    int node = (b << 8) + t;
    if (node < NN) {
        rowstart[node] = bs + ex;
        cnt[node] = v;
        dinv[node] = rsqrtf((float)(v + 1));  // +1 = self-loop
    }
    lc[t] = 0;  // reuse as cursor
    __syncthreads();
    for (int i = bs + t; i < be; i += 256) {
        int e = staged[i];
        int li = e & 255;
        int p = atomicAdd(&lc[li], 1);
        csr[ls[li] + p] = e >> 8;
    }
}

// ---------------- MFMA GEMM: hout[r] = half( (A[r] @ W) * dinv[r] ) ----------------
// 4 waves/block; wave = 16 rows x 64 cols (4 col-tiles x 4 K-steps of 16x16x32).
template <bool F32IN>
__global__ __launch_bounds__(256) void k_mgemm(const void* __restrict__ Ain,
                                               const __half* __restrict__ wt,
                                               const float* __restrict__ dinv,
                                               __half* __restrict__ hout) {
    const int tid = threadIdx.x;
    const int lane = tid & 63;
    const int wave = tid >> 6;
    const int wr = wave >> 1, wc = wave & 1;
    const int row0 = blockIdx.x * 32 + wr * 16;
    const int arow = row0 + (lane & 15);
    const int kg = lane >> 4;

    half8 afrag[4];
    if constexpr (F32IN) {
        const float* A = (const float*)Ain;
#pragma unroll
        for (int s = 0; s < 4; ++s) {
            const float* p = &A[(size_t)arow * D + s * 32 + kg * 8];
            float4 f0 = *(const float4*)p;
            float4 f1 = *(const float4*)(p + 4);
            half8 a;
            a[0] = (_Float16)f0.x; a[1] = (_Float16)f0.y;
            a[2] = (_Float16)f0.z; a[3] = (_Float16)f0.w;
            a[4] = (_Float16)f1.x; a[5] = (_Float16)f1.y;
            a[6] = (_Float16)f1.z; a[7] = (_Float16)f1.w;
            afrag[s] = a;
        }
    } else {
        const __half* A = (const __half*)Ain;
#pragma unroll
        for (int s = 0; s < 4; ++s)
            afrag[s] = *(const half8*)&A[(size_t)arow * D + s * 32 + kg * 8];
    }

    f32x4 acc[4] = {};
    const int colbase = wc * 64;
#pragma unroll
    for (int c = 0; c < 4; ++c) {
        const int col = colbase + c * 16 + (lane & 15);
#pragma unroll
        for (int s = 0; s < 4; ++s) {
            half8 b = *(const half8*)&wt[col * D + s * 32 + kg * 8];
            acc[c] = __builtin_amdgcn_mfma_f32_16x16x32_f16(afrag[s], b, acc[c], 0, 0, 0);
        }
    }

#pragma unroll
    for (int r = 0; r < 4; ++r) {
        const int row = row0 + kg * 4 + r;
        const float dv = dinv[row];
#pragma unroll
        for (int c = 0; c < 4; ++c) {
            const int col = colbase + c * 16 + (lane & 15);
            hout[(size_t)row * D + col] = __float2half(acc[c][r] * dv);
        }
    }
}

__device__ inline void add8h(float* acc, float4 raw) {
    const __half2* hp = (const __half2*)&raw;
#pragma unroll
    for (int q = 0; q < 4; ++q) {
        float2 f = __half22float2(hp[q]);
        acc[2 * q] += f.x;
        acc[2 * q + 1] += f.y;
    }
}

// ---------------- aggregation: row-major fp16 gather, one wave per node ----------
// 16 lanes x 16B cover a 128-half row; 4 neighbor-groups; prefetch 8 rows/group
// before accumulating (32 rows in flight/wave). out = relu(dinv*(self+sum)+b).
__global__ __launch_bounds__(256) void k_agg(const __half* __restrict__ hs,
                                             const int* __restrict__ rowstart,
                                             const int* __restrict__ cnt,
                                             const int* __restrict__ csr_src,
                                             const float* __restrict__ dinv,
                                             const float* __restrict__ bias,
                                             __half* __restrict__ hout) {
    const int node = blockIdx.x * 4 + (threadIdx.x >> 6);  // NN % 4 == 0, exact grid
    const int lane = threadIdx.x & 63;
    const int g = lane >> 4;           // neighbor group 0..3
    const int f8 = (lane & 15) << 3;   // feature offset (8 halves = 16B per lane)

    float acc[8] = {};
    if (g == 0) add8h(acc, *(const float4*)&hs[(size_t)node * D + f8]);  // self-loop

    const int c = cnt[node];
    const int* __restrict__ cl = csr_src + rowstart[node];

    // group g owns neighbors g, g+4, g+8, ...; prefetch 8 per pass
    int t = g;
    while (t < c) {
        float4 v[8];
#pragma unroll
        for (int i = 0; i < 8; ++i) {
            int tt = t + 4 * i;
            if (tt < c) {
                int s = cl[tt];
                v[i] = *(const float4*)&hs[(size_t)s * D + f8];
            }
        }
#pragma unroll
        for (int i = 0; i < 8; ++i) {
            int tt = t + 4 * i;
            if (tt < c) add8h(acc, v[i]);
        }
        t += 32;
    }

    // combine the 4 groups
#pragma unroll
    for (int q = 0; q < 8; ++q) {
        acc[q] += __shfl_xor(acc[q], 16);
        acc[q] += __shfl_xor(acc[q], 32);
    }

    if (g == 0) {
        const float dv = dinv[node];
        float r[8];
#pragma unroll
        for (int q = 0; q < 8; ++q) r[q] = fmaxf(fmaf(dv, acc[q], bias[f8 + q]), 0.f);
        union { float4 f; __half2 h[4]; } u;
#pragma unroll
        for (int q = 0; q < 4; ++q) u.h[q] = __floats2half2_rn(r[2 * q], r[2 * q + 1]);
        *(float4*)&hout[(size_t)node * D + f8] = u.f;
    }
}

// ---------------- output: softmax(h @ Wout + bout), fp16 h ----------------
// 8 threads per node (one per class), 32 nodes per 256-thread block
__global__ void k_out(const __half* __restrict__ h, const float* __restrict__ Wout,
                      const float* __restrict__ bout, float* __restrict__ out, int n) {
    __shared__ float ws[D * NC];
    int tid = threadIdx.x;
    for (int i = tid; i < D * NC; i += 256) ws[i] = Wout[i];
    __syncthreads();
    int node = blockIdx.x * 32 + (tid >> 3);
    int c = tid & 7;
    if (node >= n) return;
    float acc = bout[c];
    const __half* hrow = &h[(size_t)node * D];
#pragma unroll
    for (int k8 = 0; k8 < 16; ++k8) {
        float4 raw = *(const float4*)&hrow[k8 * 8];
        const __half2* hp = (const __half2*)&raw;
#pragma unroll
        for (int q = 0; q < 4; ++q) {
            float2 f = __half22float2(hp[q]);
            int k = k8 * 8 + 2 * q;
            acc += f.x * ws[k * NC + c] + f.y * ws[(k + 1) * NC + c];
        }
    }
    float m = acc;
#pragma unroll
    for (int off = 1; off < 8; off <<= 1) m = fmaxf(m, __shfl_xor(m, off));
    float e = __expf(acc - m);
    float ssum = e;
#pragma unroll
    for (int off = 1; off < 8; off <<= 1) ssum += __shfl_xor(ssum, off);
    out[(size_t)node * NC + c] = e / ssum;
}

// ---------------- launch ----------------
extern "C" void kernel_launch(void* const* d_in, const int* in_sizes, int n_in,
                              void* d_out, int out_size, void* d_ws, size_t ws_size,
                              hipStream_t stream) {
    const float* x    = (const float*)d_in[0];
    const int*   ei   = (const int*)d_in[1];   // [2][NE]: row 0 = src, row 1 = dst
    const float* W1   = (const float*)d_in[2];
    const float* b1   = (const float*)d_in[3];
    const float* W2   = (const float*)d_in[4];
    const float* b2   = (const float*)d_in[5];
    const float* Wout = (const float*)d_in[6];
    const float* bout = (const float*)d_in[7];
    float* out = (float*)d_out;

    size_t off = 0;
    char* base = (char*)d_ws;
    auto alloc = [&](size_t bytes) -> void* {
        void* p = base + off;
        off += (bytes + 255) & ~(size_t)255;
        return p;
    };
    int*    cnt      = (int*)alloc((size_t)NN * 4);
    int*    rowstart = (int*)alloc((size_t)NN * 4);
    int*    bcursor  = (int*)alloc((size_t)(NBUCK + 1) * 4);
    int*    csr      = (int*)alloc((size_t)NBUCK * BCAP * 4);  // bucket-padded
    float*  dinv     = (float*)alloc((size_t)NN * 4);
    __half* wt1      = (__half*)alloc((size_t)D * D * 2);
    __half* wt2      = (__half*)alloc((size_t)D * D * 2);
    __half* h16a     = (__half*)alloc((size_t)NN * D * 2);  // gemm output (row-major)
    __half* h16f     = (__half*)alloc((size_t)NN * D * 2);  // agg1 output (row-major)
    __half* h16b     = (__half*)alloc((size_t)NN * D * 2);  // agg2 output (row-major)
    int*    staged   = (int*)alloc((size_t)NBUCK * BCAP * 4);  // packed bucket staging
    if (off > ws_size) return;  // workspace too small; fail visibly

    const int* src = ei;
    const int* dst = ei + NE;

    // ---- CSR build: direct bucket scatter (no histogram/scan pass) ----
    int bin_grid = (NE + CHUNK - 1) / CHUNK;  // 391
    hipMemsetAsync(bcursor, 0, (size_t)NBUCK * 4, stream);
    k_bscatter<<<bin_grid, 256, 0, stream>>>(src, dst, bcursor, staged, NE);
    k_bfill<<<NBUCK + 2, 256, 0, stream>>>(staged, bcursor, rowstart, cnt, dinv, csr,
                                           W1, wt1, W2, wt2);

    int gemm_grid = NN / 32;   // 3125 exactly
    int agg_grid = NN / 4;     // 25000 exactly
    // layer 1
    k_mgemm<true><<<gemm_grid, 256, 0, stream>>>(x, wt1, dinv, h16a);
    k_agg<<<agg_grid, 256, 0, stream>>>(h16a, rowstart, cnt, csr, dinv, b1, h16f);
    // layer 2
    k_mgemm<false><<<gemm_grid, 256, 0, stream>>>(h16f, wt2, dinv, h16a);
    k_agg<<<agg_grid, 256, 0, stream>>>(h16a, rowstart, cnt, csr, dinv, b2, h16b);
    // output projection + softmax
    k_out<<<(NN + 31) / 32, 256, 0, stream>>>(h16b, Wout, bout, out, NN);
}